// Round 2
// baseline (3285.640 us; speedup 1.0000x reference)
//
#include <hip/hip_runtime.h>
#include <cstdint>
#include <cstddef>

#define NS    8192
#define HDIM  1024
#define B0DIM 64
#define FDIM  2048
#define ODIM  2048
#define NBLK  6
#define XCOLS (HDIM + B0DIM + FDIM)   // 3136

typedef __bf16 bf16_t;
typedef __bf16 bf16x8 __attribute__((ext_vector_type(8)));
typedef float  f32x4  __attribute__((ext_vector_type(4)));

__device__ inline bf16x8 cvt8(f32x4 lo, f32x4 hi) {
  bf16x8 r;
#pragma unroll
  for (int i = 0; i < 4; ++i) { r[i] = (bf16_t)lo[i]; r[i + 4] = (bf16_t)hi[i]; }
  return r;
}

// ------------------------------------------------------------------
// Elementwise kernels
// ------------------------------------------------------------------
// q = pi/4 * d^2  (d = x[:, H+B0:], fp32 in; q bf16 out; round d to bf16 first
// to track the bf16-simulated np reference)
__global__ __launch_bounds__(256) void ew_qinit(const float* __restrict__ x,
                                                bf16_t* __restrict__ q) {
  int t = blockIdx.x * 256 + threadIdx.x;      // NS*FDIM/8 threads
  int n = t >> 8;                              // FDIM/8 = 256 chunks per row
  int j = (t & 255) << 3;
  const float* p = x + (size_t)n * XCOLS + (HDIM + B0DIM) + j;
  f32x4 lo = *(const f32x4*)p;
  f32x4 hi = *(const f32x4*)(p + 4);
  bf16x8 o;
#pragma unroll
  for (int i = 0; i < 4; ++i) {
    float a = (float)(bf16_t)lo[i];
    float b = (float)(bf16_t)hi[i];
    o[i]     = (bf16_t)(0.7853981633974483f * a * a);
    o[i + 4] = (bf16_t)(0.7853981633974483f * b * b);
  }
  *(bf16x8*)(q + (size_t)n * FDIM + j) = o;
}

__global__ __launch_bounds__(256) void ew_mul(const bf16_t* a, const bf16_t* b,
                                              bf16_t* o) {
  size_t i = (size_t)(blockIdx.x * 256 + threadIdx.x) << 3;
  bf16x8 va = *(const bf16x8*)(a + i);
  bf16x8 vb = *(const bf16x8*)(b + i);
  bf16x8 vo;
#pragma unroll
  for (int k = 0; k < 8; ++k) vo[k] = (bf16_t)((float)va[k] * (float)vb[k]);
  *(bf16x8*)(o + i) = vo;
}

// o = aq * (q + sq)
__global__ __launch_bounds__(256) void ew_hid(const bf16_t* aq, const bf16_t* q,
                                              const bf16_t* sq, bf16_t* o) {
  size_t i = (size_t)(blockIdx.x * 256 + threadIdx.x) << 3;
  bf16x8 va = *(const bf16x8*)(aq + i);
  bf16x8 vq = *(const bf16x8*)(q + i);
  bf16x8 vs = *(const bf16x8*)(sq + i);
  bf16x8 vo;
#pragma unroll
  for (int k = 0; k < 8; ++k)
    vo[k] = (bf16_t)((float)va[k] * ((float)vq[k] + (float)vs[k]));
  *(bf16x8*)(o + i) = vo;
}

// o = (h + sh + rq) * dh   (o may alias h: pure elementwise, same index)
__global__ __launch_bounds__(256) void ew_u(const bf16_t* h, const bf16_t* sh,
                                            const bf16_t* rq, const bf16_t* dh,
                                            bf16_t* o) {
  size_t i = (size_t)(blockIdx.x * 256 + threadIdx.x) << 3;
  bf16x8 vh = *(const bf16x8*)(h + i);
  bf16x8 vs = *(const bf16x8*)(sh + i);
  bf16x8 vr = *(const bf16x8*)(rq + i);
  bf16x8 vd = *(const bf16x8*)(dh + i);
  bf16x8 vo;
#pragma unroll
  for (int k = 0; k < 8; ++k)
    vo[k] = (bf16_t)(((float)vh[k] + (float)vs[k] + (float)vr[k]) * (float)vd[k]);
  *(bf16x8*)(o + i) = vo;
}

// ------------------------------------------------------------------
// NT GEMM: C[n][m] = epi( sum_k A[n][k]*W[m][k] + bias[m] )
// A: NS x K (lda elems; fp32 if !ABF16 else bf16), W: M x K fp32,
// C: NS x M (bf16, or fp32 if OUTF32). fp32->bf16 conversion in staging.
// 128x128 tile, 4 waves, each wave 64x64 via 4x4 mfma_f32_16x16x32_bf16.
// EPI: 0=none 1=relu 2=C+= (C bf16)  3=q-update: C = qold - leaky(val, alpha)
// ------------------------------------------------------------------
template <int EPI, bool ABF16, bool OUTF32>
__global__ __launch_bounds__(256) void gemm_nt(
    const void* __restrict__ Av, int lda, const float* __restrict__ W, int K,
    const float* __restrict__ bias, void* __restrict__ Cv, int ldc,
    const bf16_t* __restrict__ qold, const float* __restrict__ alpha_p) {
  __shared__ __align__(16) bf16_t As[128 * 32];
  __shared__ __align__(16) bf16_t Bs[128 * 32];

  const int tid  = threadIdx.x;
  const int lane = tid & 63;
  const int wave = tid >> 6;
  const int wm   = wave & 1;   // sample-dim half (64 rows)
  const int wn   = wave >> 1;  // out-dim half (64 cols)
  const int row0 = blockIdx.y * 128;
  const int col0 = blockIdx.x * 128;

  // staging map: thread t -> rows (t>>2) and (t>>2)+64, k-chunk (t&3)*8
  const int srow  = tid >> 2;
  const int spart = tid & 3;

  const size_t aoff  = (size_t)(row0 + srow) * lda + spart * 8;
  const size_t aoff2 = (size_t)(row0 + srow + 64) * lda + spart * 8;
  const float* Wg  = W + (size_t)(col0 + srow) * K + spart * 8;
  const float* Wg2 = W + (size_t)(col0 + srow + 64) * K + spart * 8;

  bf16x8* AsW0 = (bf16x8*)&As[srow * 32 + spart * 8];
  bf16x8* AsW1 = (bf16x8*)&As[(srow + 64) * 32 + spart * 8];
  bf16x8* BsW0 = (bf16x8*)&Bs[srow * 32 + spart * 8];
  bf16x8* BsW1 = (bf16x8*)&Bs[(srow + 64) * 32 + spart * 8];

  f32x4 acc[4][4];
#pragma unroll
  for (int i = 0; i < 4; ++i)
#pragma unroll
    for (int j = 0; j < 4; ++j)
#pragma unroll
      for (int r = 0; r < 4; ++r) acc[i][j][r] = 0.0f;

  const int nk = K >> 5;

  // prefetch registers (raw; convert at LDS-write time so loads overlap MFMA)
  f32x4 wl0, wh0, wl1, wh1;
  f32x4 al0, ah0, al1, ah1;   // used when !ABF16
  bf16x8 ba0, ba1;            // used when ABF16

  auto loadk = [&](int ko) {
    wl0 = *(const f32x4*)(Wg + ko);
    wh0 = *(const f32x4*)(Wg + ko + 4);
    wl1 = *(const f32x4*)(Wg2 + ko);
    wh1 = *(const f32x4*)(Wg2 + ko + 4);
    if (ABF16) {
      const bf16_t* Ab = (const bf16_t*)Av;
      ba0 = *(const bf16x8*)(Ab + aoff + ko);
      ba1 = *(const bf16x8*)(Ab + aoff2 + ko);
    } else {
      const float* Af = (const float*)Av;
      al0 = *(const f32x4*)(Af + aoff + ko);
      ah0 = *(const f32x4*)(Af + aoff + ko + 4);
      al1 = *(const f32x4*)(Af + aoff2 + ko);
      ah1 = *(const f32x4*)(Af + aoff2 + ko + 4);
    }
  };

  loadk(0);
  const int fr   = lane & 15;
  const int quad = lane >> 4;

  for (int kt = 0; kt < nk; ++kt) {
    __syncthreads();
    if (ABF16) { *AsW0 = ba0; *AsW1 = ba1; }
    else       { *AsW0 = cvt8(al0, ah0); *AsW1 = cvt8(al1, ah1); }
    *BsW0 = cvt8(wl0, wh0);
    *BsW1 = cvt8(wl1, wh1);
    __syncthreads();
    if (kt + 1 < nk) loadk((kt + 1) * 32);

    bf16x8 af[4], bfr[4];
#pragma unroll
    for (int mt = 0; mt < 4; ++mt)
      af[mt] = *(const bf16x8*)&As[(wm * 64 + mt * 16 + fr) * 32 + quad * 8];
#pragma unroll
    for (int nt = 0; nt < 4; ++nt)
      bfr[nt] = *(const bf16x8*)&Bs[(wn * 64 + nt * 16 + fr) * 32 + quad * 8];
#pragma unroll
    for (int mt = 0; mt < 4; ++mt)
#pragma unroll
      for (int nt = 0; nt < 4; ++nt)
        acc[mt][nt] = __builtin_amdgcn_mfma_f32_16x16x32_bf16(
            af[mt], bfr[nt], acc[mt][nt], 0, 0, 0);
  }

  float alpha = 0.0f;
  if (EPI == 3) alpha = (float)(bf16_t)alpha_p[0];
  bf16_t* Cb = (bf16_t*)Cv;
  float*  Cf = (float*)Cv;

#pragma unroll
  for (int mt = 0; mt < 4; ++mt) {
#pragma unroll
    for (int nt = 0; nt < 4; ++nt) {
      int ccol = col0 + wn * 64 + nt * 16 + fr;
      float bv = (float)(bf16_t)bias[ccol];
#pragma unroll
      for (int r = 0; r < 4; ++r) {
        int crow = row0 + wm * 64 + mt * 16 + quad * 4 + r;
        size_t idx = (size_t)crow * ldc + ccol;
        float v = acc[mt][nt][r] + bv;
        if (EPI == 1) v = v > 0.0f ? v : 0.0f;
        if (EPI == 2) v += (float)Cb[idx];
        if (EPI == 3) {
          float z = v >= 0.0f ? v : alpha * v;
          v = (float)qold[idx] - z;
        }
        if (OUTF32) Cf[idx] = v; else Cb[idx] = (bf16_t)v;
      }
    }
  }
}

// sel: 0=f32A none, 1=f32A relu, 2=f32A accum, 3=bf16A none, 4=bf16A relu,
//      5=bf16A q-update, 6=bf16A none fp32-out
static inline void gemm(int sel, const void* A, int lda, const float* W, int K,
                        const float* bias, void* C, int M, const bf16_t* qold,
                        const float* alpha, hipStream_t s) {
  dim3 grid(M / 128, NS / 128), blk(256);
  switch (sel) {
    case 0: gemm_nt<0, false, false><<<grid, blk, 0, s>>>(A, lda, W, K, bias, C, M, qold, alpha); break;
    case 1: gemm_nt<1, false, false><<<grid, blk, 0, s>>>(A, lda, W, K, bias, C, M, qold, alpha); break;
    case 2: gemm_nt<2, false, false><<<grid, blk, 0, s>>>(A, lda, W, K, bias, C, M, qold, alpha); break;
    case 3: gemm_nt<0, true,  false><<<grid, blk, 0, s>>>(A, lda, W, K, bias, C, M, qold, alpha); break;
    case 4: gemm_nt<1, true,  false><<<grid, blk, 0, s>>>(A, lda, W, K, bias, C, M, qold, alpha); break;
    case 5: gemm_nt<3, true,  false><<<grid, blk, 0, s>>>(A, lda, W, K, bias, C, M, qold, alpha); break;
    case 6: gemm_nt<0, true,  true ><<<grid, blk, 0, s>>>(A, lda, W, K, bias, C, M, qold, alpha); break;
  }
}

extern "C" void kernel_launch(void* const* d_in, const int* in_sizes, int n_in,
                              void* d_out, int out_size, void* d_ws,
                              size_t ws_size, hipStream_t stream) {
  const float* x      = (const float*)d_in[0];
  const float* W_h0q  = (const float*)d_in[1];
  const float* b_h0q  = (const float*)d_in[2];
  const float* W_sq   = (const float*)d_in[3];
  const float* b_sq   = (const float*)d_in[4];
  const float* W_h0h  = (const float*)d_in[5];
  const float* b_h0h  = (const float*)d_in[6];
  const float* W_S    = (const float*)d_in[7];
  const float* b_S    = (const float*)d_in[8];
  const float* W_q0h  = (const float*)d_in[9];
  const float* b_q0h  = (const float*)d_in[10];
  const float* Wb_Aq  = (const float*)d_in[11];
  const float* bb_Aq  = (const float*)d_in[12];
  const float* Wb_Dh  = (const float*)d_in[13];
  const float* bb_Dh  = (const float*)d_in[14];
  const float* Wb_fh  = (const float*)d_in[15];
  const float* bb_fh  = (const float*)d_in[16];
  const float* Wb_hf  = (const float*)d_in[17];
  const float* bb_hf  = (const float*)d_in[18];
  const float* a_hf   = (const float*)d_in[19];
  const float* Wb_rq  = (const float*)d_in[20];
  const float* bb_rq  = (const float*)d_in[21];
  const float* W_out  = (const float*)d_in[22];
  const float* b_out  = (const float*)d_in[23];
  float* out = (float*)d_out;

  const size_t NFb = (size_t)NS * FDIM * sizeof(bf16_t);  // 33.5 MB
  const size_t NHb = (size_t)NS * HDIM * sizeof(bf16_t);  // 16.8 MB
  if (ws_size < 4 * NFb + 4 * NHb) return;

  char* ws = (char*)d_ws;
  bf16_t* q     = (bf16_t*)(ws);
  bf16_t* resS  = (bf16_t*)(ws + NFb);
  bf16_t* sumq  = (bf16_t*)(ws + 2 * NFb);
  bf16_t* tF1   = (bf16_t*)(ws + 3 * NFb);
  bf16_t* resqh = (bf16_t*)(ws + 4 * NFb);
  bf16_t* sumh  = (bf16_t*)(ws + 4 * NFb + NHb);
  bf16_t* tH1   = (bf16_t*)(ws + 4 * NFb + 2 * NHb);
  bf16_t* tH2   = (bf16_t*)(ws + 4 * NFb + 3 * NHb);
  bf16_t* Aq    = (bf16_t*)d_out;  // d_out (fp32-sized) doubles as bf16 scratch

  const int NFg = NS * FDIM / 8 / 256;  // 8192 blocks
  const int NHg = NS * HDIM / 8 / 256;  // 4096 blocks

  // q = pi/4 * d^2
  ew_qinit<<<NFg, 256, 0, stream>>>(x, q);
  // res_S_q = relu(d @ W_S^T + b_S)
  gemm(1, x + HDIM + B0DIM, XCOLS, W_S, FDIM, b_S, resS, FDIM, nullptr, nullptr, stream);
  // sum_q_const = s @ W_sq^T + b_sq ; += h0 @ W_h0q^T + b_h0q
  gemm(0, x, XCOLS, W_sq, HDIM, b_sq, sumq, FDIM, nullptr, nullptr, stream);
  gemm(2, x + HDIM, XCOLS, W_h0q, B0DIM, b_h0q, sumq, FDIM, nullptr, nullptr, stream);
  // sum_h_const = h0 @ W_h0h^T + b_h0h
  gemm(0, x + HDIM, XCOLS, W_h0h, B0DIM, b_h0h, sumh, HDIM, nullptr, nullptr, stream);
  // res_q_h = q @ W_q0h^T + b_q0h   (no relu on the initial one)
  gemm(3, q, FDIM, W_q0h, FDIM, b_q0h, resqh, HDIM, nullptr, nullptr, stream);

  for (int b = 0; b < NBLK; ++b) {
    const float* W_Aq = Wb_Aq + (size_t)b * FDIM * FDIM;
    const float* c_Aq = bb_Aq + (size_t)b * FDIM;
    const float* W_Dh = Wb_Dh + (size_t)b * HDIM * FDIM;
    const float* c_Dh = bb_Dh + (size_t)b * HDIM;
    const float* W_fh = Wb_fh + (size_t)b * HDIM * FDIM;
    const float* c_fh = bb_fh + (size_t)b * HDIM;
    const float* W_hf = Wb_hf + (size_t)b * FDIM * HDIM;
    const float* c_hf = bb_hf + (size_t)b * FDIM;
    const float* W_r  = Wb_rq + (size_t)b * HDIM * FDIM;
    const float* c_r  = bb_rq + (size_t)b * HDIM;

    // t = q * res_S_q ; A_q = t @ W_Aq^T + b_Aq
    ew_mul<<<NFg, 256, 0, stream>>>(q, resS, tF1);
    gemm(3, tF1, FDIM, W_Aq, FDIM, c_Aq, Aq, FDIM, nullptr, nullptr, stream);
    // D_h = relu(A_q @ W_Dh^T + b_Dh)
    gemm(4, Aq, FDIM, W_Dh, FDIM, c_Dh, tH1, HDIM, nullptr, nullptr, stream);
    // hid = A_q * (q + sum_q_const) ; h = relu(hid @ W_fh^T + b_fh)
    ew_hid<<<NFg, 256, 0, stream>>>(Aq, q, sumq, tF1);
    gemm(4, tF1, FDIM, W_fh, FDIM, c_fh, tH2, HDIM, nullptr, nullptr, stream);
    // u = (h + sum_h_const + res_q_h) * D_h   (in-place over h)
    ew_u<<<NHg, 256, 0, stream>>>(tH2, sumh, resqh, tH1, tH2);
    // q = q - leaky(u @ W_hf^T + b_hf, a[b])   (fused epilogue)
    gemm(5, tH2, HDIM, W_hf, HDIM, c_hf, q, FDIM, q, a_hf + b, stream);
    // res_q_h = relu(q @ W_resq^T + b_resq)
    gemm(4, q, FDIM, W_r, FDIM, c_r, resqh, HDIM, nullptr, nullptr, stream);
  }

  // out = q @ W_out^T + b_out  (fp32 output)
  gemm(6, q, FDIM, W_out, FDIM, b_out, out, ODIM, nullptr, nullptr, stream);
}